// Round 1
// baseline (269.133 us; speedup 1.0000x reference)
//
#include <hip/hip_runtime.h>
#include <cstdint>
#include <cstddef>

// AdMSoftmax loss, N=8192, D=256, S=1, M=0.4, unique-label branch.
//   G = x1 @ x2^T  (bf16 MFMA, never materialized)
//   rownormsq_i = x1_i^T (X2^T X2) x1_i ; colnormsq_j = x2_j^T (X1^T X1) x2_j
//   rowExp_i = sum_j exp(G_ij / rn_i) ; colExp_j = sum_i exp(G_ij / cn_j)  (fused epilogue)
//   L12_i = num - log(exp(num) + rowExp_i - exp(sim_ii)), num = sim_ii - 0.4
//   out = [loss, L12[8192], L21[8192]]

#define NROWS 8192
#define DIMK 256
#define MARGIN 0.4f
#define LOG2E 1.4426950408889634f

typedef short short8 __attribute__((ext_vector_type(8)));
typedef float f32x4 __attribute__((ext_vector_type(4)));

__device__ __forceinline__ unsigned short f2bf(float f) {
  union { float f; unsigned u; } v; v.f = f;
  unsigned r = (v.u + 0x7fffu + ((v.u >> 16) & 1u)) >> 16;  // RNE
  return (unsigned short)r;
}

__device__ __forceinline__ void gl_lds16(const void* g, void* l) {
  __builtin_amdgcn_global_load_lds((const __attribute__((address_space(1))) void*)g,
                                   (__attribute__((address_space(3))) void*)l, 16, 0, 0);
}

// ---- convert x -> bf16 rows + exact fp32 diag dot (one wave per row) ----
__global__ __launch_bounds__(256)
void k_conv_diag(const float* __restrict__ x1, const float* __restrict__ x2,
                 unsigned short* __restrict__ Ab, unsigned short* __restrict__ Bb,
                 float* __restrict__ diag) {
  const int row = blockIdx.x * 4 + (threadIdx.x >> 6);
  const int l = threadIdx.x & 63;
  const float4 a = ((const float4*)(x1 + (size_t)row * DIMK))[l];
  const float4 b = ((const float4*)(x2 + (size_t)row * DIMK))[l];
  ushort4 ua, ub;
  ua.x = f2bf(a.x); ua.y = f2bf(a.y); ua.z = f2bf(a.z); ua.w = f2bf(a.w);
  ub.x = f2bf(b.x); ub.y = f2bf(b.y); ub.z = f2bf(b.z); ub.w = f2bf(b.w);
  ((ushort4*)(Ab + (size_t)row * DIMK))[l] = ua;
  ((ushort4*)(Bb + (size_t)row * DIMK))[l] = ub;
  float d = a.x * b.x + a.y * b.y + a.z * b.z + a.w * b.w;
#pragma unroll
  for (int m = 1; m < 64; m <<= 1) d += __shfl_xor(d, m);
  if (l == 0) diag[row] = d;
}

// ---- M = X^T X (256x256), K split 16 ways, fp32 atomic accumulate ----
__global__ __launch_bounds__(256)
void k_syrk(const float* __restrict__ x1, const float* __restrict__ x2,
            float* __restrict__ M1, float* __restrict__ M2) {
  __shared__ float Xa[32][34];
  __shared__ float Xb[32][34];
  const int t = threadIdx.x;
  const int mat = blockIdx.z >> 4;
  const int seg = blockIdx.z & 15;
  const float* X = mat ? x2 : x1;
  float* Mo = mat ? M2 : M1;
  const int a0 = blockIdx.y * 32;
  const int b0 = blockIdx.x * 32;
  const int tx = t & 15, ty = t >> 4;
  float a00 = 0.f, a01 = 0.f, a10 = 0.f, a11 = 0.f;
  const int nb = seg * 512;
  for (int n0 = nb; n0 < nb + 512; n0 += 32) {
#pragma unroll
    for (int q = 0; q < 4; ++q) {
      const int e = q * 256 + t;
      const int rr = e >> 5, cc = e & 31;
      Xa[rr][cc] = X[(size_t)(n0 + rr) * DIMK + a0 + cc];
      Xb[rr][cc] = X[(size_t)(n0 + rr) * DIMK + b0 + cc];
    }
    __syncthreads();
#pragma unroll 8
    for (int r = 0; r < 32; ++r) {
      const float2 av = *(const float2*)&Xa[r][2 * ty];
      const float2 bv = *(const float2*)&Xb[r][2 * tx];
      a00 += av.x * bv.x; a01 += av.x * bv.y;
      a10 += av.y * bv.x; a11 += av.y * bv.y;
    }
    __syncthreads();
  }
  float* dst = Mo + (size_t)(a0 + 2 * ty) * 256 + b0 + 2 * tx;
  atomicAdd(dst, a00);
  atomicAdd(dst + 1, a01);
  atomicAdd(dst + 256, a10);
  atomicAdd(dst + 257, a11);
}

__global__ void k_convM(const float* __restrict__ M1, unsigned short* __restrict__ M1b,
                        const float* __restrict__ M2, unsigned short* __restrict__ M2b) {
  const int i = (blockIdx.x * 256 + threadIdx.x) * 2;
  M1b[i] = f2bf(M1[i]); M1b[i + 1] = f2bf(M1[i + 1]);
  M2b[i] = f2bf(M2[i]); M2b[i + 1] = f2bf(M2[i + 1]);
}

// ---- shared MFMA GEMM core: C = A(rows,K=256) * B(rows,K=256)^T, 128x128 tile
// EPI=0: sumsq epilogue   sumsq[row] += sum_c C[row][c] * Xf[row][c]
// EPI=1: exp epilogue     rowExp[row] += sum_c exp(C/rn), colExp[col] += sum_r exp(C/cn)
template <int EPI>
__global__ __launch_bounds__(256)
void k_gemm(const unsigned short* __restrict__ A, const unsigned short* __restrict__ B,
            const float* __restrict__ Xf, float* __restrict__ sumsq,
            const float* __restrict__ rowInv, const float* __restrict__ colInv,
            float* __restrict__ rowExp, float* __restrict__ colExp) {
  __shared__ unsigned short As[128 * 32];
  __shared__ unsigned short Bs[128 * 32];
  __shared__ float cRow[128];
  __shared__ float cCol[128];

  const int t = threadIdx.x;
  const int w = t >> 6;
  const int l = t & 63;
  const int quad = l >> 4;
  const int l15 = l & 15;
  const int row0 = blockIdx.x * 128;
  const int col0 = blockIdx.y * 128;
  const int wr = (w >> 1) * 64;  // wave's row base in tile
  const int wc = (w & 1) * 64;   // wave's col base in tile

  f32x4 acc[4][4] = {};

  const int sr0 = l >> 2;   // row within 16-row chunk
  const int slot = l & 3;   // 8-element k-slot

  for (int k0 = 0; k0 < DIMK; k0 += 32) {
#pragma unroll
    for (int p = 0; p < 2; ++p) {
      const int c = w * 2 + p;           // chunk 0..7 (16 rows each)
      const int r = c * 16 + sr0;
      // XOR-swizzle which k-slot this lane fetches so ds_read_b128 is conflict-free
      const int sc = (slot ^ ((r >> 1) & 3)) << 3;
      gl_lds16(A + (size_t)(row0 + r) * DIMK + k0 + sc, (void*)&As[c * 512 + l * 8]);
      gl_lds16(B + (size_t)(col0 + r) * DIMK + k0 + sc, (void*)&Bs[c * 512 + l * 8]);
    }
    __syncthreads();
    short8 af[4], bg[4];
#pragma unroll
    for (int i = 0; i < 4; ++i) {
      const int ra = wr + i * 16 + l15;
      af[i] = *(const short8*)&As[ra * 32 + ((quad ^ ((ra >> 1) & 3)) << 3)];
      const int rb = wc + i * 16 + l15;
      bg[i] = *(const short8*)&Bs[rb * 32 + ((quad ^ ((rb >> 1) & 3)) << 3)];
    }
#pragma unroll
    for (int i = 0; i < 4; ++i)
#pragma unroll
      for (int j = 0; j < 4; ++j)
        acc[i][j] = __builtin_amdgcn_mfma_f32_16x16x32_bf16(af[i], bg[j], acc[i][j], 0, 0, 0);
    __syncthreads();
  }

  // C/D layout: row_local = wr + i*16 + quad*4 + r ; col_local = wc + j*16 + l15
  if (EPI == 0) {
#pragma unroll
    for (int i = 0; i < 4; ++i) {
#pragma unroll
      for (int r = 0; r < 4; ++r) {
        const int lr = wr + i * 16 + quad * 4 + r;
        const float* xr = Xf + (size_t)(row0 + lr) * DIMK + col0 + wc;
        float rp = 0.f;
#pragma unroll
        for (int j = 0; j < 4; ++j) rp += acc[i][j][r] * xr[j * 16 + l15];
        rp += __shfl_xor(rp, 1); rp += __shfl_xor(rp, 2);
        rp += __shfl_xor(rp, 4); rp += __shfl_xor(rp, 8);
        if (l15 == 0) atomicAdd(&sumsq[row0 + lr], rp);
      }
    }
  } else {
    if (t < 128) cRow[t] = LOG2E * rowInv[row0 + t];
    else cCol[t - 128] = LOG2E * colInv[col0 + t - 128];
    __syncthreads();
    float cj[4];
#pragma unroll
    for (int j = 0; j < 4; ++j) cj[j] = cCol[wc + j * 16 + l15];
    float colpart[4] = {0.f, 0.f, 0.f, 0.f};
#pragma unroll
    for (int i = 0; i < 4; ++i) {
#pragma unroll
      for (int r = 0; r < 4; ++r) {
        const int lr = wr + i * 16 + quad * 4 + r;
        const float ci = cRow[lr];
        float rp = 0.f;
#pragma unroll
        for (int j = 0; j < 4; ++j) {
          const float g = acc[i][j][r];
          rp += exp2f(g * ci);
          colpart[j] += exp2f(g * cj[j]);
        }
        rp += __shfl_xor(rp, 1); rp += __shfl_xor(rp, 2);
        rp += __shfl_xor(rp, 4); rp += __shfl_xor(rp, 8);
        if (l15 == 0) atomicAdd(&rowExp[row0 + lr], rp);
      }
    }
#pragma unroll
    for (int j = 0; j < 4; ++j) {
      float cp = colpart[j];
      cp += __shfl_xor(cp, 16); cp += __shfl_xor(cp, 32);
      if (l < 16) atomicAdd(&colExp[col0 + wc + j * 16 + l15], cp);
    }
  }
}

__global__ void k_rsqrt(const float* __restrict__ rowsq, const float* __restrict__ colsq,
                        float* __restrict__ rowInv, float* __restrict__ colInv) {
  const int i = blockIdx.x * 256 + threadIdx.x;
  if (i < NROWS) rowInv[i] = rsqrtf(rowsq[i]);
  else colInv[i - NROWS] = rsqrtf(colsq[i - NROWS]);
}

__global__ __launch_bounds__(256)
void k_finalize(const float* __restrict__ rowInv, const float* __restrict__ colInv,
                const float* __restrict__ diag, const float* __restrict__ rowExp,
                const float* __restrict__ colExp, float* __restrict__ out,
                float* __restrict__ lossAcc) {
  const int i = blockIdx.x * 256 + threadIdx.x;
  const float d = diag[i];
  const float s1 = d * rowInv[i];
  const float s2 = d * colInv[i];
  const float n1 = s1 - MARGIN;
  const float n2 = s2 - MARGIN;
  const float L1 = n1 - logf(rowExp[i] - expf(s1) + expf(n1));
  const float L2 = n2 - logf(colExp[i] - expf(s2) + expf(n2));
  out[1 + i] = L1;
  out[1 + NROWS + i] = L2;
  float sum = L1 + L2;
#pragma unroll
  for (int m = 1; m < 64; m <<= 1) sum += __shfl_xor(sum, m);
  __shared__ float red[4];
  if ((threadIdx.x & 63) == 0) red[threadIdx.x >> 6] = sum;
  __syncthreads();
  if (threadIdx.x == 0) atomicAdd(lossAcc, red[0] + red[1] + red[2] + red[3]);
}

__global__ void k_loss(const float* __restrict__ lossAcc, float* __restrict__ out) {
  if (threadIdx.x == 0) out[0] = -lossAcc[0] * (1.0f / (float)NROWS);
}

extern "C" void kernel_launch(void* const* d_in, const int* in_sizes, int n_in,
                              void* d_out, int out_size, void* d_ws, size_t ws_size,
                              hipStream_t stream) {
  const float* x1 = (const float*)d_in[0];
  const float* x2 = (const float*)d_in[1];
  float* out = (float*)d_out;
  char* ws = (char*)d_ws;

  unsigned short* Ab = (unsigned short*)(ws + 0);         // 4 MB  x1 bf16
  unsigned short* Bb = (unsigned short*)(ws + 4194304);   // 4 MB  x2 bf16
  float* M1 = (float*)(ws + 8388608);                     // 256 KB  X1^T X1
  float* M2 = (float*)(ws + 8650752);                     // 256 KB  X2^T X2
  float* rowsq = (float*)(ws + 8912896);                  // 32 KB
  float* colsq = (float*)(ws + 8945664);                  // 32 KB
  float* rowExp = (float*)(ws + 8978432);                 // 32 KB
  float* colExp = (float*)(ws + 9011200);                 // 32 KB
  float* lossAcc = (float*)(ws + 9043968);                // 16 B
  unsigned short* M1b = (unsigned short*)(ws + 9043984);  // 128 KB
  unsigned short* M2b = (unsigned short*)(ws + 9175056);  // 128 KB
  float* rowInv = (float*)(ws + 9306128);                 // 32 KB
  float* colInv = (float*)(ws + 9338896);                 // 32 KB
  float* diag = (float*)(ws + 9371664);                   // 32 KB

  // zero all atomic accumulators (M1..lossAcc contiguous region)
  hipMemsetAsync(ws + 8388608, 0, 655376, stream);

  k_conv_diag<<<NROWS / 4, 256, 0, stream>>>(x1, x2, Ab, Bb, diag);
  k_syrk<<<dim3(8, 8, 32), 256, 0, stream>>>(x1, x2, M1, M2);
  k_convM<<<128, 256, 0, stream>>>(M1, M1b, M2, M2b);
  // rownormsq: Y = X1*M2 (M2 symmetric -> usable directly as B), dot with x1
  k_gemm<0><<<dim3(64, 2), 256, 0, stream>>>(Ab, M2b, x1, rowsq,
                                             nullptr, nullptr, nullptr, nullptr);
  k_gemm<0><<<dim3(64, 2), 256, 0, stream>>>(Bb, M1b, x2, colsq,
                                             nullptr, nullptr, nullptr, nullptr);
  k_rsqrt<<<64, 256, 0, stream>>>(rowsq, colsq, rowInv, colInv);
  // main GEMM + exp-sum epilogue
  k_gemm<1><<<dim3(64, 64), 256, 0, stream>>>(Ab, Bb, nullptr, nullptr,
                                              rowInv, colInv, rowExp, colExp);
  k_finalize<<<NROWS / 256, 256, 0, stream>>>(rowInv, colInv, diag, rowExp, colExp,
                                              out, lossAcc);
  k_loss<<<1, 64, 0, stream>>>(lossAcc, out);
}

// Round 2
// 193.604 us; speedup vs baseline: 1.3901x; 1.3901x over previous
//
#include <hip/hip_runtime.h>
#include <cstdint>
#include <cstddef>

// AdMSoftmax loss, N=8192, D=256, S=1, M=0.4, unique-label branch.
//   G = x1 @ x2^T (bf16 MFMA, never materialized)
//   rownormsq_i = x1_i^T (X2^T X2) x1_i ; colnormsq_j = x2_j^T (X1^T X1) x2_j
//   rowExp_i = sum_j exp(G_ij/rn_i) ; colExp_j = sum_i exp(G_ij/cn_j) (fused epilogue)
//   L12_i = num - log(exp(num) + rowExp_i - exp(sim_ii)), num = sim_ii - 0.4
//   out = [loss, L12[8192], L21[8192]]

#define NROWS 8192
#define DIMK 256
#define MARGIN 0.4f
#define LOG2E 1.4426950408889634f

typedef short short8 __attribute__((ext_vector_type(8)));
typedef float f32x4 __attribute__((ext_vector_type(4)));

__device__ __forceinline__ unsigned short f2bf(float f) {
  union { float f; unsigned u; } v; v.f = f;
  unsigned r = (v.u + 0x7fffu + ((v.u >> 16) & 1u)) >> 16;  // RNE
  return (unsigned short)r;
}

__device__ __forceinline__ void gl_lds16(const void* g, void* l) {
  __builtin_amdgcn_global_load_lds((const __attribute__((address_space(1))) void*)g,
                                   (__attribute__((address_space(3))) void*)l, 16, 0, 0);
}

// ---- convert x -> bf16 rows + exact fp32 diag dot (one wave per row) ----
__global__ __launch_bounds__(256)
void k_conv_diag(const float* __restrict__ x1, const float* __restrict__ x2,
                 unsigned short* __restrict__ Ab, unsigned short* __restrict__ Bb,
                 float* __restrict__ diag) {
  const int row = blockIdx.x * 4 + (threadIdx.x >> 6);
  const int l = threadIdx.x & 63;
  const float4 a = ((const float4*)(x1 + (size_t)row * DIMK))[l];
  const float4 b = ((const float4*)(x2 + (size_t)row * DIMK))[l];
  ushort4 ua, ub;
  ua.x = f2bf(a.x); ua.y = f2bf(a.y); ua.z = f2bf(a.z); ua.w = f2bf(a.w);
  ub.x = f2bf(b.x); ub.y = f2bf(b.y); ub.z = f2bf(b.z); ub.w = f2bf(b.w);
  ((ushort4*)(Ab + (size_t)row * DIMK))[l] = ua;
  ((ushort4*)(Bb + (size_t)row * DIMK))[l] = ub;
  float d = a.x * b.x + a.y * b.y + a.z * b.z + a.w * b.w;
#pragma unroll
  for (int m = 1; m < 64; m <<= 1) d += __shfl_xor(d, m);
  if (l == 0) diag[row] = d;
}

// ---- M = X^T X (256x256) via bf16 MFMA, 64x64 tiles, 16 K-segments, atomics ----
__global__ __launch_bounds__(256)
void k_syrk(const unsigned short* __restrict__ Ab, const unsigned short* __restrict__ Bb,
            float* __restrict__ M1, float* __restrict__ M2) {
  __shared__ unsigned short As[64 * 32];
  __shared__ unsigned short Bs[64 * 32];
  const int t = threadIdx.x, w = t >> 6, l = t & 63, quad = l >> 4, l15 = l & 15;
  const int mat = blockIdx.z & 1;
  const int kseg = blockIdx.z >> 1;  // 0..15, 512 rows each
  const unsigned short* X = mat ? Bb : Ab;
  float* Mo = mat ? M2 : M1;
  const int a0 = blockIdx.y * 64, b0 = blockIdx.x * 64;
  const int wr = (w >> 1) * 32, wc = (w & 1) * 32;
  f32x4 acc[2][2] = {};
  const int nn = t & 31, cb = t >> 5;  // n within chunk / col-block 0..7
  const int c0 = cb * 8;
  const int nb = kseg * 512;
  for (int n0 = nb; n0 < nb + 512; n0 += 32) {
    short8 va = *(const short8*)(X + (size_t)(n0 + nn) * DIMK + a0 + c0);
    short8 vb = *(const short8*)(X + (size_t)(n0 + nn) * DIMK + b0 + c0);
    // transposed store: As[c][n], k-slot XOR-swizzled to match frag reads
#pragma unroll
    for (int i = 0; i < 8; ++i) {
      const int c = c0 + i;
      const int sl = (((nn >> 3) ^ ((c >> 1) & 3)) << 3) + (nn & 7);
      As[c * 32 + sl] = va[i];
      Bs[c * 32 + sl] = vb[i];
    }
    __syncthreads();
    short8 af[2], bg[2];
#pragma unroll
    for (int i = 0; i < 2; ++i) {
      const int ra = wr + i * 16 + l15;
      af[i] = *(const short8*)&As[ra * 32 + ((quad ^ ((ra >> 1) & 3)) << 3)];
      const int rb = wc + i * 16 + l15;
      bg[i] = *(const short8*)&Bs[rb * 32 + ((quad ^ ((rb >> 1) & 3)) << 3)];
    }
#pragma unroll
    for (int i = 0; i < 2; ++i)
#pragma unroll
      for (int j = 0; j < 2; ++j)
        acc[i][j] = __builtin_amdgcn_mfma_f32_16x16x32_bf16(af[i], bg[j], acc[i][j], 0, 0, 0);
    __syncthreads();
  }
#pragma unroll
  for (int i = 0; i < 2; ++i)
#pragma unroll
    for (int j = 0; j < 2; ++j)
#pragma unroll
      for (int r = 0; r < 4; ++r) {
        const int lr = wr + i * 16 + quad * 4 + r;
        const int lc = wc + j * 16 + l15;
        atomicAdd(&Mo[(size_t)(a0 + lr) * 256 + b0 + lc], acc[i][j][r]);
      }
}

__global__ void k_convM(const float* __restrict__ M1, unsigned short* __restrict__ M1b,
                        const float* __restrict__ M2, unsigned short* __restrict__ M2b) {
  const int i = (blockIdx.x * 256 + threadIdx.x) * 2;
  M1b[i] = f2bf(M1[i]); M1b[i + 1] = f2bf(M1[i + 1]);
  M2b[i] = f2bf(M2[i]); M2b[i + 1] = f2bf(M2[i + 1]);
}

// ---- MFMA GEMM core: C = A(rows,K=256) * B(rows,K=256)^T, 128x128 tile,
// double-buffered LDS, ONE barrier per K-iter.
// EPI=0 (grid.z selects side): sumsq[row] += sum_c C[row][c]*Xf[row][c]
// EPI=1: rowExp[row] += sum_c exp(C*ci), colExp[col] += sum_r exp(C*cj)
template <int EPI>
__global__ __launch_bounds__(256)
void k_gemm(const unsigned short* __restrict__ Abuf, const unsigned short* __restrict__ Bbuf,
            const unsigned short* __restrict__ M1b, const unsigned short* __restrict__ M2b,
            const float* __restrict__ x1, const float* __restrict__ x2,
            float* __restrict__ rowsq, float* __restrict__ colsq,
            float* __restrict__ rowExp, float* __restrict__ colExp) {
  __shared__ unsigned short As[2][4096];
  __shared__ unsigned short Bs[2][4096];
  __shared__ float cRow[128];
  __shared__ float cCol[128];

  const unsigned short* A;
  const unsigned short* B;
  const float* Xf = nullptr;
  float* sq = nullptr;
  if (EPI == 0) {
    if (blockIdx.z == 0) { A = Abuf; B = M2b; Xf = x1; sq = rowsq; }
    else                 { A = Bbuf; B = M1b; Xf = x2; sq = colsq; }
  } else {
    A = Abuf; B = Bbuf;
  }

  const int t = threadIdx.x;
  const int w = t >> 6;
  const int l = t & 63;
  const int quad = l >> 4;
  const int l15 = l & 15;
  const int row0 = blockIdx.x * 128;
  const int col0 = blockIdx.y * 128;
  const int wr = (w >> 1) * 64;
  const int wc = (w & 1) * 64;

  if (EPI == 1) {  // prefetch scales before the K-loop; first barrier publishes
    if (t < 128) cRow[t] = LOG2E * rsqrtf(rowsq[row0 + t]);
    else cCol[t - 128] = LOG2E * rsqrtf(colsq[col0 + t - 128]);
  }

  f32x4 acc[4][4] = {};

  const int sr0 = l >> 2;
  const int slot = l & 3;
  const int cA = w * 2, cB = w * 2 + 1;
  const int rA = cA * 16 + sr0, rB = cB * 16 + sr0;
  const int scA = (slot ^ ((rA >> 1) & 3)) << 3;
  const int scB = (slot ^ ((rB >> 1) & 3)) << 3;
  const unsigned short* pA0 = A + (size_t)(row0 + rA) * DIMK + scA;
  const unsigned short* pA1 = A + (size_t)(row0 + rB) * DIMK + scB;
  const unsigned short* pB0 = B + (size_t)(col0 + rA) * DIMK + scA;
  const unsigned short* pB1 = B + (size_t)(col0 + rB) * DIMK + scB;
  const int dA0 = cA * 512 + l * 8, dA1 = cB * 512 + l * 8;

  // preload k-chunk 0 into buffer 0
  gl_lds16(pA0, &As[0][dA0]);
  gl_lds16(pA1, &As[0][dA1]);
  gl_lds16(pB0, &Bs[0][dA0]);
  gl_lds16(pB1, &Bs[0][dA1]);

#pragma unroll
  for (int k0 = 0; k0 < 8; ++k0) {
    const int cur = k0 & 1;
    __syncthreads();  // drains cur-buffer loads; all waves aligned
    if (k0 < 7) {     // prefetch next chunk into the other buffer
      const int nxt = cur ^ 1;
      gl_lds16(pA0 + (k0 + 1) * 32, &As[nxt][dA0]);
      gl_lds16(pA1 + (k0 + 1) * 32, &As[nxt][dA1]);
      gl_lds16(pB0 + (k0 + 1) * 32, &Bs[nxt][dA0]);
      gl_lds16(pB1 + (k0 + 1) * 32, &Bs[nxt][dA1]);
    }
    short8 af[4], bg[4];
#pragma unroll
    for (int i = 0; i < 4; ++i) {
      const int ra = wr + i * 16 + l15;
      af[i] = *(const short8*)&As[cur][ra * 32 + ((quad ^ ((ra >> 1) & 3)) << 3)];
      const int rb = wc + i * 16 + l15;
      bg[i] = *(const short8*)&Bs[cur][rb * 32 + ((quad ^ ((rb >> 1) & 3)) << 3)];
    }
#pragma unroll
    for (int i = 0; i < 4; ++i)
#pragma unroll
      for (int j = 0; j < 4; ++j)
        acc[i][j] = __builtin_amdgcn_mfma_f32_16x16x32_bf16(af[i], bg[j], acc[i][j], 0, 0, 0);
  }

  // C/D layout: row_local = wr + i*16 + quad*4 + r ; col_local = wc + j*16 + l15
  if (EPI == 0) {
#pragma unroll
    for (int i = 0; i < 4; ++i) {
#pragma unroll
      for (int r = 0; r < 4; ++r) {
        const int lr = wr + i * 16 + quad * 4 + r;
        const float* xr = Xf + (size_t)(row0 + lr) * DIMK + col0 + wc;
        float rp = 0.f;
#pragma unroll
        for (int j = 0; j < 4; ++j) rp += acc[i][j][r] * xr[j * 16 + l15];
        rp += __shfl_xor(rp, 1); rp += __shfl_xor(rp, 2);
        rp += __shfl_xor(rp, 4); rp += __shfl_xor(rp, 8);
        if (l15 == 0) atomicAdd(&sq[row0 + lr], rp);
      }
    }
  } else {
    float cj[4];
#pragma unroll
    for (int j = 0; j < 4; ++j) cj[j] = cCol[wc + j * 16 + l15];
    float colpart[4] = {0.f, 0.f, 0.f, 0.f};
#pragma unroll
    for (int i = 0; i < 4; ++i) {
#pragma unroll
      for (int r = 0; r < 4; ++r) {
        const int lr = wr + i * 16 + quad * 4 + r;
        const float ci = cRow[lr];
        float rp = 0.f;
#pragma unroll
        for (int j = 0; j < 4; ++j) {
          const float g = acc[i][j][r];
          rp += __builtin_amdgcn_exp2f(g * ci);
          colpart[j] += __builtin_amdgcn_exp2f(g * cj[j]);
        }
        rp += __shfl_xor(rp, 1); rp += __shfl_xor(rp, 2);
        rp += __shfl_xor(rp, 4); rp += __shfl_xor(rp, 8);
        if (l15 == 0) atomicAdd(&rowExp[row0 + lr], rp);
      }
    }
#pragma unroll
    for (int j = 0; j < 4; ++j) {
      float cp = colpart[j];
      cp += __shfl_xor(cp, 16); cp += __shfl_xor(cp, 32);
      if (l < 16) atomicAdd(&colExp[col0 + wc + j * 16 + l15], cp);
    }
  }
}

// ---- fused finalize + loss: single block, double-precision total ----
__global__ __launch_bounds__(1024)
void k_final(const float* __restrict__ rowsq, const float* __restrict__ colsq,
             const float* __restrict__ diag, const float* __restrict__ rowExp,
             const float* __restrict__ colExp, float* __restrict__ out) {
  const int t = threadIdx.x;
  double part = 0.0;
#pragma unroll
  for (int it = 0; it < 8; ++it) {
    const int i = it * 1024 + t;
    const float d = diag[i];
    const float s1 = d * rsqrtf(rowsq[i]);
    const float s2 = d * rsqrtf(colsq[i]);
    const float n1 = s1 - MARGIN, n2 = s2 - MARGIN;
    const float L1 = n1 - logf(rowExp[i] - expf(s1) + expf(n1));
    const float L2 = n2 - logf(colExp[i] - expf(s2) + expf(n2));
    out[1 + i] = L1;
    out[1 + NROWS + i] = L2;
    part += (double)L1 + (double)L2;
  }
#pragma unroll
  for (int m = 1; m < 64; m <<= 1) part += __shfl_xor(part, m);
  __shared__ double red[16];
  if ((t & 63) == 0) red[t >> 6] = part;
  __syncthreads();
  if (t == 0) {
    double s = 0.0;
#pragma unroll
    for (int i = 0; i < 16; ++i) s += red[i];
    out[0] = (float)(-s / (double)NROWS);
  }
}

extern "C" void kernel_launch(void* const* d_in, const int* in_sizes, int n_in,
                              void* d_out, int out_size, void* d_ws, size_t ws_size,
                              hipStream_t stream) {
  const float* x1 = (const float*)d_in[0];
  const float* x2 = (const float*)d_in[1];
  float* out = (float*)d_out;
  char* ws = (char*)d_ws;

  unsigned short* Ab = (unsigned short*)(ws);             // 4 MB  x1 bf16
  unsigned short* Bb = (unsigned short*)(ws + 4194304);   // 4 MB  x2 bf16
  float* M1 = (float*)(ws + 8388608);                     // 256 KB  X1^T X1 (fp32 acc)
  float* M2 = (float*)(ws + 8650752);                     // 256 KB  X2^T X2
  float* rowsq = (float*)(ws + 8912896);                  // 32 KB
  float* colsq = (float*)(ws + 8945664);                  // 32 KB
  float* rowExp = (float*)(ws + 8978432);                 // 32 KB
  float* colExp = (float*)(ws + 9011200);                 // 32 KB
  unsigned short* M1b = (unsigned short*)(ws + 9043968);  // 128 KB
  unsigned short* M2b = (unsigned short*)(ws + 9175040);  // 128 KB
  float* diag = (float*)(ws + 9306112);                   // 32 KB

  // zero atomic accumulators (M1..colExp contiguous 640 KB)
  hipMemsetAsync(ws + 8388608, 0, 655360, stream);

  k_conv_diag<<<NROWS / 4, 256, 0, stream>>>(x1, x2, Ab, Bb, diag);
  k_syrk<<<dim3(4, 4, 32), 256, 0, stream>>>(Ab, Bb, M1, M2);
  k_convM<<<128, 256, 0, stream>>>(M1, M1b, M2, M2b);
  k_gemm<0><<<dim3(64, 2, 2), 256, 0, stream>>>(Ab, Bb, M1b, M2b, x1, x2,
                                                rowsq, colsq, rowExp, colExp);
  k_gemm<1><<<dim3(64, 64), 256, 0, stream>>>(Ab, Bb, M1b, M2b, x1, x2,
                                              rowsq, colsq, rowExp, colExp);
  k_final<<<1, 1024, 0, stream>>>(rowsq, colsq, diag, rowExp, colExp, out);
}